// Round 12
// baseline (10548.920 us; speedup 1.0000x reference)
//
#include <hip/hip_runtime.h>
#include <math.h>

#define N_NODES 10000
#define N_EDGES 320000
#define NBLK 512               // persistent grid: 2 blocks/CU x 256 CU -> all co-resident
#define TPB 256
#define NWAVE (NBLK * 4)       // 2048 waves
#define NPW 5                  // nodes per wave: 2048*5 = 10240 >= 10000

// ---------------- agent-scope (IC-coherent) access helpers ----------------
// XCD L2s are not cross-coherent; agent-scope atomics operate at the Infinity
// Cache (coherent point). All cross-block-visible state inside persistent
// kernels goes through these. No L2 dirty data -> no wbL2 cost at barriers.
__device__ __forceinline__ float aload(const float* p) {
  return __hip_atomic_load(p, __ATOMIC_RELAXED, __HIP_MEMORY_SCOPE_AGENT);
}
__device__ __forceinline__ void astore(float* p, float v) {
  __hip_atomic_store(p, v, __ATOMIC_RELAXED, __HIP_MEMORY_SCOPE_AGENT);
}
__device__ __forceinline__ float2 aload2(const float* p) {
  unsigned long long u = __hip_atomic_load((const unsigned long long*)p,
                                           __ATOMIC_RELAXED, __HIP_MEMORY_SCOPE_AGENT);
  union { unsigned long long u; float2 f; } c; c.u = u; return c.f;
}
__device__ __forceinline__ void astore2(float* p, float2 v) {
  union { unsigned long long u; float2 f; } c; c.f = v;
  __hip_atomic_store((unsigned long long*)p, c.u, __ATOMIC_RELAXED, __HIP_MEMORY_SCOPE_AGENT);
}

// Lean global barrier: 8 padded counters (64 blocks each -> ~1us of adds),
// thread-0 polls the sum. __syncthreads drains each wave's vmcnt before the
// add (compiler emits s_waitcnt vmcnt(0) before s_barrier), so all block
// stores are at the coherent point before the add is visible. Bounded spin
// converts a visibility bug into FAIL instead of hang.
__device__ __forceinline__ void gbarrier(unsigned* dn, unsigned target) {
  __syncthreads();
  if (threadIdx.x == 0) {
    __hip_atomic_fetch_add(&dn[(blockIdx.x & 7) * 64], 1u,
                           __ATOMIC_RELAXED, __HIP_MEMORY_SCOPE_AGENT);
    int cap = 2000000;
    while (cap--) {
      unsigned s = 0;
#pragma unroll
      for (int i = 0; i < 8; i++)
        s += __hip_atomic_load(&dn[i * 64], __ATOMIC_RELAXED, __HIP_MEMORY_SCOPE_AGENT);
      if (s >= target) break;
      __builtin_amdgcn_s_sleep(1);
    }
  }
  __syncthreads();
}

// ---------------- edge_index dtype detection ----------------
__global__ void k_detect(const int* __restrict__ ei, int* __restrict__ flag) {
  __shared__ int any_nz;
  if (threadIdx.x == 0) any_nz = 0;
  __syncthreads();
  if (ei[2 * threadIdx.x + 1] != 0) atomicOr(&any_nz, 1);
  __syncthreads();
  if (threadIdx.x == 0) *flag = (any_nz == 0) ? 1 : 0;  // 1 => int64 layout
}

__device__ __forceinline__ int2 load_edge(const int* __restrict__ ei, int e, int is64) {
  if (is64) return make_int2(ei[2 * e], ei[2 * N_EDGES + 2 * e]);
  return make_int2(ei[e], ei[N_EDGES + e]);
}

// ---------------- preprocessing ----------------

__global__ void k_init(float* __restrict__ deg, int* __restrict__ cnt,
                       unsigned* __restrict__ dn) {
  int i = blockIdx.x * blockDim.x + threadIdx.x;
  if (i < N_NODES) { deg[i] = 0.f; cnt[i] = 0; }
  if (i < 3 * 512) dn[i] = 0u;   // 3 barrier-counter sets
}

__global__ void k_deg(const int* __restrict__ ei, const float* __restrict__ w,
                      const int* __restrict__ flag,
                      float* __restrict__ deg, int* __restrict__ cnt) {
  const int is64 = *flag;
  int e = blockIdx.x * blockDim.x + threadIdx.x;
  if (e < N_EDGES) {
    int2 sd = load_edge(ei, e, is64);
    atomicAdd(&deg[sd.x], w[e]);
    atomicAdd(&cnt[sd.y], 1);
  }
}

__global__ __launch_bounds__(1024) void k_scan(const float* __restrict__ deg,
                                               float* __restrict__ dis,
                                               const int* __restrict__ cnt,
                                               int* __restrict__ row_ptr,
                                               int* __restrict__ cur) {
  __shared__ int sbuf[1024];
  const int tid = threadIdx.x;
  for (int i = tid; i < N_NODES; i += 1024) {
    float d = deg[i];
    dis[i] = d > 0.f ? 1.f / sqrtf(d) : 0.f;
    cur[i] = 0;
  }
  __syncthreads();
  int run = 0;
  for (int base = 0; base < N_NODES; base += 1024) {
    int v = (base + tid < N_NODES) ? cnt[base + tid] : 0;
    sbuf[tid] = v;
    __syncthreads();
    for (int o = 1; o < 1024; o <<= 1) {
      int t = (tid >= o) ? sbuf[tid - o] : 0;
      __syncthreads();
      sbuf[tid] += t;
      __syncthreads();
    }
    if (base + tid < N_NODES) row_ptr[base + tid + 1] = run + sbuf[tid];
    int tot = sbuf[1023];
    __syncthreads();
    run += tot;
  }
  if (tid == 0) row_ptr[0] = 0;
}

__global__ void k_fill(const int* __restrict__ ei, const float* __restrict__ w,
                       const int* __restrict__ flag, const float* __restrict__ dis,
                       const int* __restrict__ row_ptr, int* __restrict__ cur,
                       int2* __restrict__ edat) {
  const int is64 = *flag;
  int e = blockIdx.x * blockDim.x + threadIdx.x;
  if (e < N_EDGES) {
    int2 sd = load_edge(ei, e, is64);
    int p = row_ptr[sd.y] + atomicAdd(&cur[sd.y], 1);
    float v = -dis[sd.x] * w[e] * dis[sd.y];
    edat[p] = make_int2(sd.x, __float_as_int(v));
  }
}

// transpose W (K,CI,CO) -> Wt (K,CO,CI)
__global__ void k_tr(const float* __restrict__ W, float* __restrict__ Wt,
                     int K, int CI, int CO) {
  int i = blockIdx.x * blockDim.x + threadIdx.x;
  int tot = K * CI * CO;
  if (i < tot) {
    int k = i / (CI * CO), r = i % (CI * CO);
    int ci = r / CO, co = r % CO;
    Wt[k * CI * CO + co * CI + ci] = W[i];
  }
}

// ---------------- gather (60-ch rows, lane=channel, IC-coherent loads) ----------------
__device__ __forceinline__ float gather60a(const int2* __restrict__ edat, int e0, int e1,
                                           const float* __restrict__ t, int cl) {
  float a0 = 0.f, a1 = 0.f, a2 = 0.f, a3 = 0.f, a4 = 0.f, a5 = 0.f, a6 = 0.f, a7 = 0.f;
  int e = e0;
  for (; e + 7 < e1; e += 8) {
    int2 d0 = edat[e],     d1 = edat[e + 1], d2 = edat[e + 2], d3 = edat[e + 3];
    int2 d4 = edat[e + 4], d5 = edat[e + 5], d6 = edat[e + 6], d7 = edat[e + 7];
    a0 += __int_as_float(d0.y) * aload(t + d0.x * 60 + cl);
    a1 += __int_as_float(d1.y) * aload(t + d1.x * 60 + cl);
    a2 += __int_as_float(d2.y) * aload(t + d2.x * 60 + cl);
    a3 += __int_as_float(d3.y) * aload(t + d3.x * 60 + cl);
    a4 += __int_as_float(d4.y) * aload(t + d4.x * 60 + cl);
    a5 += __int_as_float(d5.y) * aload(t + d5.x * 60 + cl);
    a6 += __int_as_float(d6.y) * aload(t + d6.x * 60 + cl);
    a7 += __int_as_float(d7.y) * aload(t + d7.x * 60 + cl);
  }
  for (; e < e1; e++) { int2 d = edat[e]; a0 += __int_as_float(d.y) * aload(t + d.x * 60 + cl); }
  return ((a0 + a1) + (a2 + a3)) + ((a4 + a5) + (a6 + a7));
}

// ---------------- persistent layer kernels (plain launch + lean barrier) ----------------
// Math identical to round-9 coop kernels (PASSED, absmax 0.0); only the sync
// (gbarrier vs grid.sync) and t-buffer memory ops (agent atomics) changed.

// Layer 1: CI=2, CO=60, K=200.
__global__ __launch_bounds__(TPB, 2) void k_layer_narrow(
    const int* __restrict__ rowp, const int2* __restrict__ edat,
    const float* __restrict__ x,      // stride 2 (input, coherent via launch boundary)
    const float* __restrict__ Wt,     // [200][60][2]
    const float* __restrict__ bias,
    float* __restrict__ bufA, float* __restrict__ bufB,  // stride 2, IC-atomics
    float* __restrict__ h_out,        // stride 60, normal stores (flushed at kernel end)
    unsigned* __restrict__ dn)
{
  const int wid = threadIdx.x >> 6, lane = threadIdx.x & 63;
  const int gw = blockIdx.x * 4 + wid;
  const int co = (lane < 60) ? lane : 0;
  int nodes[NPW], starts[NPW], ends[NPW];
  float A0[NPW], A1[NPW], B0[NPW], B1[NPW], acc[NPW];
#pragma unroll
  for (int s = 0; s < NPW; s++) {
    int nd = gw + s * NWAVE; nodes[s] = nd;
    bool v = nd < N_NODES;
    starts[s] = v ? rowp[nd] : 0;
    ends[s]   = v ? rowp[nd + 1] : 0;
  }
#pragma unroll
  for (int s = 0; s < NPW; s++) {
    bool v = nodes[s] < N_NODES;
    float x0 = 0.f, x1 = 0.f;
    if (v) { float2 xv = *reinterpret_cast<const float2*>(x + nodes[s] * 2); x0 = xv.x; x1 = xv.y; }
    float s0 = 0.f, s1 = 0.f;
    for (int e = starts[s] + lane; e < ends[s]; e += 64) {
      int2 d = edat[e]; float w = __int_as_float(d.y);
      float2 tv = *reinterpret_cast<const float2*>(x + d.x * 2);
      s0 += w * tv.x; s1 += w * tv.y;
    }
#pragma unroll
    for (int o = 32; o; o >>= 1) { s0 += __shfl_xor(s0, o); s1 += __shfl_xor(s1, o); }
    A0[s] = x0; A1[s] = x1; B0[s] = s0; B1[s] = s1;
    if (v && lane == 0) astore2(bufB + nodes[s] * 2, make_float2(s0, s1));
    float2 w0 = *reinterpret_cast<const float2*>(Wt + co * 2);
    float2 w1 = *reinterpret_cast<const float2*>(Wt + (60 + co) * 2);
    acc[s] = bias[co] + x0 * w0.x + x1 * w0.y + s0 * w1.x + s1 * w1.y;
  }
  const float* rb = bufB; float* wb = bufA;
  unsigned g = 0;
  for (int k = 2; k < 200; k++) {
    g++; gbarrier(dn, (unsigned)NBLK * g);   // step k-1 writes visible before step k reads
    const float2 wk = *reinterpret_cast<const float2*>(Wt + ((size_t)k * 60 + co) * 2);
#pragma unroll
    for (int s = 0; s < NPW; s++) {
      float s0 = 0.f, s1 = 0.f;
      for (int e = starts[s] + lane; e < ends[s]; e += 64) {
        int2 d = edat[e]; float w = __int_as_float(d.y);
        float2 tv = aload2(rb + d.x * 2);
        s0 += w * tv.x; s1 += w * tv.y;
      }
#pragma unroll
      for (int o = 32; o; o >>= 1) { s0 += __shfl_xor(s0, o); s1 += __shfl_xor(s1, o); }
      float t0 = 2.f * s0 - A0[s], t1 = 2.f * s1 - A1[s];
      A0[s] = B0[s]; A1[s] = B1[s]; B0[s] = t0; B1[s] = t1;
      if (nodes[s] < N_NODES && lane == 0) astore2(wb + nodes[s] * 2, make_float2(t0, t1));
      acc[s] += t0 * wk.x + t1 * wk.y;
    }
    const float* t = rb; rb = wb; wb = (float*)t;
  }
#pragma unroll
  for (int s = 0; s < NPW; s++)
    if (nodes[s] < N_NODES && lane < 60) {
      float v = acc[s];
      h_out[nodes[s] * 60 + lane] = v / (1.f + expf(-v));  // silu
    }
}

// Layers 2/3: CI=60, CO in {60,30}. FINAL folds h@W4 + sigmoid epilogue.
template <int CO, bool FINAL>
__global__ __launch_bounds__(TPB, 2) void k_layer_wide(
    const int* __restrict__ rowp, const int2* __restrict__ edat,
    const float* __restrict__ h_in,   // stride 60 (prev kernel output, flushed)
    const float* __restrict__ Wt,     // [K][CO][60]
    const float* __restrict__ bias, int K,
    float* __restrict__ bufA, float* __restrict__ bufB,  // stride 60, IC-atomics
    float* __restrict__ h_out,        // !FINAL: stride 60
    const float* __restrict__ W4,     // FINAL only (30,)
    float* __restrict__ out,          // FINAL only
    unsigned* __restrict__ dn)
{
  __shared__ __align__(16) float ts[4][NPW][64];
  const int wid = threadIdx.x >> 6, lane = threadIdx.x & 63;
  const int gw = blockIdx.x * 4 + wid;
  const int cl = (lane < 60) ? lane : 59;
  const int co = (lane < CO) ? lane : 0;
  int nodes[NPW], starts[NPW], ends[NPW];
  float A[NPW], Bv[NPW], acc[NPW];
#pragma unroll
  for (int s = 0; s < NPW; s++) {
    int nd = gw + s * NWAVE; nodes[s] = nd;
    bool v = nd < N_NODES;
    starts[s] = v ? rowp[nd] : 0;
    ends[s]   = v ? rowp[nd + 1] : 0;
    A[s] = v ? h_in[nd * 60 + cl] : 0.f;                       // T0
    float gt = gather60a(edat, starts[s], ends[s], h_in, cl);  // T1
    Bv[s] = gt;
    if (v && lane < 60) astore(bufB + nd * 60 + lane, gt);
    acc[s] = bias[co];
  }
  // acc += T0 @ W[0] + T1 @ W[1]
#pragma unroll
  for (int s = 0; s < NPW; s++) ts[wid][s][lane] = A[s];
  __builtin_amdgcn_wave_barrier();
  {
    const float* wr = Wt + (size_t)co * 60;
#pragma unroll
    for (int c4 = 0; c4 < 15; c4++) {
      float4 w = *reinterpret_cast<const float4*>(wr + c4 * 4);
#pragma unroll
      for (int s = 0; s < NPW; s++) {
        float4 tv = *reinterpret_cast<const float4*>(&ts[wid][s][c4 * 4]);
        acc[s] += w.x * tv.x + w.y * tv.y + w.z * tv.z + w.w * tv.w;
      }
    }
  }
  __builtin_amdgcn_wave_barrier();
#pragma unroll
  for (int s = 0; s < NPW; s++) ts[wid][s][lane] = Bv[s];
  __builtin_amdgcn_wave_barrier();
  {
    const float* wr = Wt + ((size_t)CO + co) * 60;
#pragma unroll
    for (int c4 = 0; c4 < 15; c4++) {
      float4 w = *reinterpret_cast<const float4*>(wr + c4 * 4);
#pragma unroll
      for (int s = 0; s < NPW; s++) {
        float4 tv = *reinterpret_cast<const float4*>(&ts[wid][s][c4 * 4]);
        acc[s] += w.x * tv.x + w.y * tv.y + w.z * tv.z + w.w * tv.w;
      }
    }
  }
  const float* rb = bufB; float* wb = bufA;
  unsigned g = 0;
  for (int k = 2; k < K; k++) {
    g++; gbarrier(dn, (unsigned)NBLK * g);   // step k-1 writes visible before step k reads
#pragma unroll
    for (int s = 0; s < NPW; s++) {
      float gt = gather60a(edat, starts[s], ends[s], rb, cl);
      float tn = 2.f * gt - A[s];
      A[s] = Bv[s]; Bv[s] = tn;
      if (nodes[s] < N_NODES && lane < 60) astore(wb + nodes[s] * 60 + lane, tn);
      ts[wid][s][lane] = tn;
    }
    __builtin_amdgcn_wave_barrier();
    const float* wr = Wt + ((size_t)k * CO + co) * 60;
#pragma unroll
    for (int c4 = 0; c4 < 15; c4++) {
      float4 w = *reinterpret_cast<const float4*>(wr + c4 * 4);
#pragma unroll
      for (int s = 0; s < NPW; s++) {
        float4 tv = *reinterpret_cast<const float4*>(&ts[wid][s][c4 * 4]);
        acc[s] += w.x * tv.x + w.y * tv.y + w.z * tv.z + w.w * tv.w;
      }
    }
    const float* t = rb; rb = wb; wb = (float*)t;
  }
  if constexpr (!FINAL) {
#pragma unroll
    for (int s = 0; s < NPW; s++)
      if (nodes[s] < N_NODES && lane < CO) {
        float v = acc[s];
        h_out[nodes[s] * 60 + lane] = v / (1.f + expf(-v));  // silu
      }
  } else {
#pragma unroll
    for (int s = 0; s < NPW; s++) {
      float p = 0.f;
      if (lane < 30) { float v = acc[s]; p = (v / (1.f + expf(-v))) * W4[lane]; }
#pragma unroll
      for (int o = 32; o; o >>= 1) p += __shfl_xor(p, o);
      if (lane == 0 && nodes[s] < N_NODES) out[nodes[s]] = 1.f / (1.f + expf(-p));
    }
  }
}

// ---------------- host ----------------

extern "C" void kernel_launch(void* const* d_in, const int* in_sizes, int n_in,
                              void* d_out, int out_size, void* d_ws, size_t ws_size,
                              hipStream_t stream) {
  const float* x  = (const float*)d_in[0];
  const int*   ei = (const int*)d_in[1];
  const float* ew = (const float*)d_in[2];
  const float* W1 = (const float*)d_in[3];
  const float* b1 = (const float*)d_in[4];
  const float* W2 = (const float*)d_in[5];
  const float* b2 = (const float*)d_in[6];
  const float* W3 = (const float*)d_in[7];
  const float* b3 = (const float*)d_in[8];
  const float* W4 = (const float*)d_in[9];
  float* out = (float*)d_out;

  char* ws = (char*)d_ws;
  size_t off = 0;
  auto alloc = [&](size_t bytes) {
    void* p = ws + off;
    off += (bytes + 255) & ~size_t(255);
    return p;
  };
  float*    deg  = (float*)alloc(N_NODES * 4);
  float*    dis  = (float*)alloc(N_NODES * 4);
  int*      cnt  = (int*)alloc(N_NODES * 4);
  int*      cur  = (int*)alloc(N_NODES * 4);
  int*      rowp = (int*)alloc((N_NODES + 1) * 4);
  int2*     edat = (int2*)alloc(N_EDGES * 8);
  int*      flag = (int*)alloc(256);
  unsigned* dn   = (unsigned*)alloc(3 * 512 * 4);   // 3 barrier sets x 8 counters x 64-pad
  float*    Wt1  = (float*)alloc(200 * 2 * 60 * 4);
  float*    Wt2  = (float*)alloc(200 * 60 * 60 * 4);
  float*    Wt3  = (float*)alloc(20 * 60 * 30 * 4);
  float*    tA   = (float*)alloc(N_NODES * 60 * 4);
  float*    tB   = (float*)alloc(N_NODES * 60 * 4);
  float*    h1   = (float*)alloc(N_NODES * 60 * 4);
  float*    h2   = (float*)alloc(N_NODES * 60 * 4);

  k_detect<<<1, 256, 0, stream>>>(ei, flag);
  k_init<<<(N_NODES + 255) / 256, 256, 0, stream>>>(deg, cnt, dn);
  k_deg<<<(N_EDGES + 255) / 256, 256, 0, stream>>>(ei, ew, flag, deg, cnt);
  k_scan<<<1, 1024, 0, stream>>>(deg, dis, cnt, rowp, cur);
  k_fill<<<(N_EDGES + 255) / 256, 256, 0, stream>>>(ei, ew, flag, dis, rowp, cur, edat);
  k_tr<<<(200 * 2 * 60 + 255) / 256, 256, 0, stream>>>(W1, Wt1, 200, 2, 60);
  k_tr<<<(200 * 60 * 60 + 255) / 256, 256, 0, stream>>>(W2, Wt2, 200, 60, 60);
  k_tr<<<(20 * 60 * 30 + 255) / 256, 256, 0, stream>>>(W3, Wt3, 20, 60, 30);

  k_layer_narrow<<<NBLK, TPB, 0, stream>>>(rowp, edat, x, Wt1, b1, tA, tB, h1, dn);
  k_layer_wide<60, false><<<NBLK, TPB, 0, stream>>>(rowp, edat, h1, Wt2, b2, 200,
                                                    tA, tB, h2, W4, out, dn + 512);
  k_layer_wide<30, true><<<NBLK, TPB, 0, stream>>>(rowp, edat, h2, Wt3, b3, 20,
                                                   tA, tB, h2, W4, out, dn + 1024);
}